// Round 8
// baseline (341.279 us; speedup 1.0000x reference)
//
#include <hip/hip_runtime.h>

typedef short bf16x8_t __attribute__((ext_vector_type(8)));
typedef float f32x4_t __attribute__((ext_vector_type(4)));

#define NTOK 577
#define QPAD 640   // q/k row padding (rows 577..639 zeroed)
#define MPAD 608   // m range actually iterated (19*32)
#define NSTEP 19
#define VTILES 80  // v tiles of 8 tokens each (covers n 0..639, pad zeroed)
#define VTILE_ELEMS 6144  // 768 hd * 8 n
#define LOG2E 1.44269504088896340736f

__device__ __forceinline__ unsigned short f2bf(float f) {  // RNE (prepass only)
  unsigned u = __builtin_bit_cast(unsigned, f);
  u += 0x7FFFu + ((u >> 16) & 1u);
  return (unsigned short)(u >> 16);
}
__device__ __forceinline__ float headw(const float* wts, int h) {
  float w0 = wts[0], w1 = wts[1], w2 = wts[2];
  return (h < 8) ? (w0 + w1 + w2) : ((h < 10) ? (w1 + w2) : w2);
}
__device__ __forceinline__ unsigned rangemask(int lo, int hi) {
  lo = lo < 0 ? 0 : lo; hi = hi > 32 ? 32 : hi;
  if (hi <= lo) return 0u;
  unsigned mh = (hi >= 32) ? 0xFFFFFFFFu : ((1u << hi) - 1u);
  unsigned ml = (1u << lo) - 1u;
  return mh & ~ml;
}

// ---------------- prepass v3: 8-token tiles, all sides coalesced ----------------
// q prescale includes LOG2E: logits emerge in log2 domain -> exp2 in hma.
extern "C" __global__ __launch_bounds__(256) void prep_x3(
    const float* __restrict__ x, const float* __restrict__ wts,
    unsigned short* __restrict__ qbf, unsigned short* __restrict__ kbf,
    unsigned short* __restrict__ vbf) {
  __shared__ unsigned short vT[8][768];    // 12288 B
  const int tid = threadIdx.x;
  const int mc = blockIdx.x;               // 0..79
  const int n0 = mc * 8;
  const int b = blockIdx.y;
  const float w0 = wts[0], w1 = wts[1], w2 = wts[2];
  const float wA = w0 + w1 + w2, wB = w1 + w2, wC = w2;
  const float* xb = x + (size_t)b * NTOK * 2304;
#pragma unroll 2
  for (int p = 0; p < 18; ++p) {           // 8 rows x 576 float4 = 4608 / 256
    int i = p * 256 + tid;
    int nl = i / 576;
    int c4 = i - nl * 576;
    int n = n0 + nl;
    float4 v = {0.f, 0.f, 0.f, 0.f};
    if (n < NTOK) v = *(const float4*)(xb + (size_t)n * 2304 + c4 * 4);
    int sec = c4 / 192;                    // 0=q 1=k 2=v (wave-uniform: 576=9*64)
    int cc = c4 - sec * 192;
    int h = cc >> 4, d4 = cc & 15;
    if (sec == 2) {
      ushort4 o;
      o.x = f2bf(v.x); o.y = f2bf(v.y); o.z = f2bf(v.z); o.w = f2bf(v.w);
      *(ushort4*)&vT[nl][cc * 4] = o;
    } else {
      float s = 1.f;
      if (sec == 0) {
        float w = (h < 8) ? wA : ((h < 10) ? wB : wC);
        s = w * w * 0.125f * LOG2E;
      }
      ushort4 o;
      o.x = f2bf(v.x * s); o.y = f2bf(v.y * s); o.z = f2bf(v.z * s); o.w = f2bf(v.w * s);
      unsigned short* dst = (sec == 0) ? qbf : kbf;
      *(ushort4*)(dst + ((size_t)(b * 12 + h)) * QPAD * 64 + (size_t)n * 64 + d4 * 4) = o;
    }
  }
  __syncthreads();
  unsigned short* tile = vbf + (size_t)(b * VTILES + mc) * VTILE_ELEMS;
#pragma unroll
  for (int t = 0; t < 3; ++t) {
    int hd = t * 256 + tid;
    bf16x8_t val;
#pragma unroll
    for (int jj = 0; jj < 8; ++jj) val[jj] = (short)vT[jj][hd];
    *(bf16x8_t*)(tile + (size_t)hd * 8) = val;
  }
}

// ---------------- prepass: tables + precomputed G-fragments ----------------
extern "C" __global__ __launch_bounds__(256) void prep_tab(
    const float* __restrict__ wts,
    const float* __restrict__ tkv, const float* __restrict__ tkh,
    const float* __restrict__ tvv, const float* __restrict__ tvh,
    unsigned short* __restrict__ tkb, unsigned short* __restrict__ tvb,
    unsigned short* __restrict__ gfb) {
  int tid = threadIdx.x, bx = blockIdx.x;
  if (bx < 48) {
    int cid = bx * 256 + tid;
    int d4 = cid & 15, t = (cid >> 4) & 31, tb = (cid >> 9) & 1, h = cid >> 10;
    float s = 1.f / headw(wts, h);
    const float* src = tb ? tkh : tkv;
    float4 v = {0,0,0,0};
    if (t < 30) v = *(const float4*)(src + t * 64 + d4 * 4);
    ushort4 o;
    o.x = f2bf(v.x * s); o.y = f2bf(v.y * s); o.z = f2bf(v.z * s); o.w = f2bf(v.w * s);
    *(ushort4*)(tkb + (((size_t)(h * 2 + tb)) * 32 + t) * 64 + d4 * 4) = o;
  } else if (bx == 48) {
    for (int i = 0; i < 16; ++i) {
      int id = tid * 16 + i;              // 4096 = 2*64*32, t fastest
      int t = id & 31, d = (id >> 5) & 63, tb = id >> 11;
      const float* src = tb ? tvh : tvv;
      tvb[id] = (t < 30) ? f2bf(src[t * 64 + d]) : (unsigned short)0;
    }
  } else {
    int id = (bx - 49) * 256 + tid;       // 0..4863 = ((tb*19+step)*2+gt)*64+lane
    int lane = id & 63, gt = (id >> 6) & 1;
    int sg = id >> 7;                     // tb*19+step
    int step = sg % 19, tb = sg / 19;
    int l15 = lane & 15, quad = lane >> 4;
    int g = gt * 16 + l15;
    int m0 = step * 32;
    unsigned mask = 0u;
    if (g < 25) {
      if (g == 24) {
        mask = rangemask(NTOK - m0, MPAD - m0);
        if (step == 0) mask |= 1u;
      } else if (tb == 0) {
        mask = rangemask(24 * g + 1 - m0, 24 * g + 25 - m0);
      } else {
        int j0 = (g + 1 - m0) % 24; if (j0 < 0) j0 += 24;
        for (int j = j0; j < 32; j += 24) {
          int m = m0 + j;
          if (m >= 1 && m < NTOK) mask |= (1u << j);
        }
      }
    }
    unsigned short o[8];
#pragma unroll
    for (int j = 0; j < 8; ++j) {
      int m_loc = quad * 8 + j;
      o[j] = ((mask >> m_loc) & 1u) ? (unsigned short)0x3F80 : (unsigned short)0;
    }
    *(ushort4*)(gfb + (size_t)id * 8) = *(ushort4*)&o[0];
    *(ushort4*)(gfb + (size_t)id * 8 + 4) = *(ushort4*)&o[4];
  }
}

// ---------------- main kernel v8: v4/v5 verified structure, LDS 25.1KB ----------------
// Sequential-tb prologue/epilogue halves the union scratch: 29216 -> 25120 B
// => 6 blocks/CU (was 5, measured ~2.75 resident). Loop body identical to R4.
struct __align__(16) SMem {
  float qg_t[2][25][68];               // 13600 B  bias by group, g-major (pad 68 for b128)
  float l_s[64];                       // 256 B    softmax denominators
  union {                              // 11264 B
    struct { float qv_t[64][30]; } pro;              // 7680 (one tb at a time)
    struct { unsigned short P_s[2][64][44]; } loop;  // 11264 (double-buffered)
    struct { float sv_f[64][30]; } epi;              // 7680 (one tb at a time)
  } u;
};  // 25120 B -> 6 blocks/CU

extern "C" __global__ __launch_bounds__(256, 6) void hma_kernel(
    const unsigned short* __restrict__ qbf, const unsigned short* __restrict__ kbf,
    const unsigned short* __restrict__ vbf, const unsigned short* __restrict__ tkb,
    const unsigned short* __restrict__ tvb, const unsigned short* __restrict__ gfb,
    const float* __restrict__ wts, float* __restrict__ out) {
  __shared__ SMem sm;
  const int tid = threadIdx.x;
  const int wave = tid >> 6, lane = tid & 63, quad = lane >> 4, l15 = lane & 15;
  const int rg = wave & 1;      // n-half (32 rows)
  const int cg = wave >> 1;     // m-half within step / d-half / table id
  const int tb_w = cg;
  // XCD swizzle: colocate the 10 n-tiles of each (b,h) on one XCD (120*B % 8 == 0 always)
  const int nwg = gridDim.x * gridDim.y * gridDim.z;
  const int L = blockIdx.x + gridDim.x * (blockIdx.y + gridDim.y * blockIdx.z);
  const int wid = (L & 7) * (nwg >> 3) + (L >> 3);
  const int n0 = (wid % 10) * 64;
  const int rest = wid / 10;
  const int h = rest % 12, b = rest / 12;
  const float w = headw(wts, h);

  const unsigned short* qb = qbf + ((size_t)(b * 12 + h)) * QPAD * 64;
  const unsigned short* kb = kbf + ((size_t)(b * 12 + h)) * QPAD * 64;
  const unsigned short* gfp = gfb + ((size_t)tb_w * 19) * 1024 + lane * 8;

  // q fragments: registers only, straight from global (pre-scaled bf16)
  bf16x8_t qa[2][2];
  for (int sub = 0; sub < 2; ++sub)
    for (int kk = 0; kk < 2; ++kk)
      qa[sub][kk] = *(const bf16x8_t*)(qb + (size_t)(n0 + rg * 32 + sub * 16 + l15) * 64 + kk * 32 + quad * 8);

  // ---- prologue: bias tables, one tb at a time (half the scratch) ----
  // wave (rg,cg): rows rg*32.., t-range tt=cg for the CURRENT tb.
  for (int tb = 0; tb < 2; ++tb) {
    const unsigned short* tkp = tkb + ((size_t)(h * 2 + tb)) * 32 * 64;
    const int tt = cg;
    for (int sub = 0; sub < 2; ++sub) {
      f32x4_t acc = {0.f, 0.f, 0.f, 0.f};
      for (int kk = 0; kk < 2; ++kk) {
        bf16x8_t bb = *(const bf16x8_t*)(tkp + (size_t)(tt * 16 + l15) * 64 + kk * 32 + quad * 8);
        acc = __builtin_amdgcn_mfma_f32_16x16x32_bf16(qa[sub][kk], bb, acc, 0, 0, 0);
      }
      int t = tt * 16 + l15;
      if (t < 30)
        for (int r = 0; r < 4; ++r)
          sm.u.pro.qv_t[rg * 32 + sub * 16 + quad * 4 + r][t] = acc[r];
    }
    __syncthreads();
    // pre-scatter rel-k bias by group (transposed: qg_t[tb][g][n])
    for (int p = tid; p < 25 * 64; p += 256) {
      int g = p / 64, n = p % 64;
      int n_g = n0 + n;
      int t;
      if (n_g == 0 || n_g >= NTOK || g == 24) t = 0;
      else {
        int base = tb ? ((n_g - 1) % 24) : ((n_g - 1) / 24);
        int dq = g - base; dq = dq < -14 ? -14 : (dq > 14 ? 14 : dq);
        t = dq + 15;
      }
      sm.qg_t[tb][g][n] = sm.u.pro.qv_t[n][t];
    }
    __syncthreads();   // qv_t reads done before next tb overwrite / loop union reuse
  }

  // per-thread m-group trackers
  const int m_loc = cg * 16 + l15;
  int rmv, cmv;
  if (m_loc == 0) { rmv = 0; cmv = -1; }
  else { rmv = (m_loc - 1) / 24; cmv = (m_loc - 1) - rmv * 24; }
  const bool cls_lane = (m_loc == 0);

  f32x4_t oacc[2][2] = {{{0,0,0,0},{0,0,0,0}},{{0,0,0,0},{0,0,0,0}}};
  f32x4_t rsacc[2][2] = {{{0,0,0,0},{0,0,0,0}},{{0,0,0,0},{0,0,0,0}}};

  // direct-global fragment base pointers
  const unsigned short* kfr = kb + (size_t)(cg * 16 + l15) * 64 + quad * 8;
  const unsigned short* vfr = vbf + (size_t)b * VTILES * VTILE_ELEMS + h * 512
                              + (size_t)(cg * 32 + l15) * 8;
  bf16x8_t kf0 = *(const bf16x8_t*)(kfr);        // step 0 k-frags (rows 0..31)
  bf16x8_t kf1 = *(const bf16x8_t*)(kfr + 32);

  for (int step = 0; step < NSTEP; ++step) {
    const int m0 = step * 32;
    const int buf = step & 1;
    // G fragments for this step (L2-hot; issue early, use late)
    bf16x8_t gv0 = *(const bf16x8_t*)(gfp + (size_t)step * 1024);
    bf16x8_t gv1 = *(const bf16x8_t*)(gfp + (size_t)step * 1024 + 512);
    // S = q_hat . k^T  (two n-subtiles per wave) — k frags already in regs
    f32x4_t s[2] = {{0,0,0,0},{0,0,0,0}};
    for (int sub = 0; sub < 2; ++sub) {
      s[sub] = __builtin_amdgcn_mfma_f32_16x16x32_bf16(qa[sub][0], kf0, s[sub], 0, 0, 0);
      s[sub] = __builtin_amdgcn_mfma_f32_16x16x32_bf16(qa[sub][1], kf1, s[sub], 0, 0, 0);
    }
    // v B-frags for THIS step: contiguous 16B/lane from tiled vbf (issue early)
    const unsigned short* vt = vfr + (size_t)(m0 / 8 + quad) * VTILE_ELEMS;
    bf16x8_t vf0 = *(const bf16x8_t*)(vt);
    bf16x8_t vf1 = *(const bf16x8_t*)(vt + 128);
    // k prefetch for NEXT step (rows 608..639 are zero pad on last iter)
    kf0 = *(const bf16x8_t*)(kfr + (size_t)(m0 + 32) * 64);
    kf1 = *(const bf16x8_t*)(kfr + (size_t)(m0 + 32) * 64 + 32);
    // rel bias + exp2 -> P (logits already in log2 domain via q prescale)
    const int m_g = m0 + m_loc;
    int ur = rmv, uc = cmv;
    if (cls_lane && step == 0) { ur = 24; uc = 24; }
    const bool mpad = (m_g >= NTOK);
    for (int sub = 0; sub < 2; ++sub) {
      int nbase = rg * 32 + sub * 16 + quad * 4;
      f32x4_t g0 = *(const f32x4_t*)&sm.qg_t[0][ur][nbase];
      f32x4_t g1 = *(const f32x4_t*)&sm.qg_t[1][uc][nbase];
      for (int r = 0; r < 4; ++r) {
        float logit = s[sub][r] + g0[r] + g1[r];
        float p = __builtin_exp2f(logit);
        if (mpad) p = 0.f;
        unsigned u = __builtin_bit_cast(unsigned, p);
        sm.u.loop.P_s[buf][nbase + r][m_loc] = (unsigned short)((u + 0x8000u) >> 16);
      }
    }
    { int c = cmv + 8; int carry = (c >= 24); cmv = carry ? c - 24 : c; rmv += 1 + carry; }
    __syncthreads();                           // P_s[buf] ready (only barrier per step)
    // A fragments (P) shared by PV and G
    bf16x8_t pa[2];
    for (int sub = 0; sub < 2; ++sub)
      pa[sub] = *(const bf16x8_t*)&sm.u.loop.P_s[buf][rg * 32 + sub * 16 + l15][quad * 8];
    // O += P.V  (v frags from regs)
    for (int sub = 0; sub < 2; ++sub) {
      oacc[sub][0] = __builtin_amdgcn_mfma_f32_16x16x32_bf16(pa[sub], vf0, oacc[sub][0], 0, 0, 0);
      oacc[sub][1] = __builtin_amdgcn_mfma_f32_16x16x32_bf16(pa[sub], vf1, oacc[sub][1], 0, 0, 0);
    }
    // rowsum += P.G
    for (int sub = 0; sub < 2; ++sub) {
      rsacc[sub][0] = __builtin_amdgcn_mfma_f32_16x16x32_bf16(pa[sub], gv0, rsacc[sub][0], 0, 0, 0);
      rsacc[sub][1] = __builtin_amdgcn_mfma_f32_16x16x32_bf16(pa[sub], gv1, rsacc[sub][1], 0, 0, 0);
    }
  }

  // ---- epilogue: one tb at a time through the halved sv scratch ----
  __syncthreads();   // last P_s reads done before union reuse
  for (int tb = 0; tb < 2; ++tb) {
    for (int e = tid; e < 64 * 30; e += 256) (&sm.u.epi.sv_f[0][0])[e] = 0.f;
    __syncthreads();
    if (cg == tb) {    // this wave's rsacc belongs to table tb
      for (int sub = 0; sub < 2; ++sub)
        for (int gt = 0; gt < 2; ++gt) {
          int g = gt * 16 + l15;
          if (g < 25) {
            for (int r = 0; r < 4; ++r) {
              int n_loc = rg * 32 + sub * 16 + quad * 4 + r;
              int n_g = n0 + n_loc;
              int t;
              if (n_g == 0 || n_g >= NTOK || g == 24) t = 0;
              else {
                int base = tb ? ((n_g - 1) % 24) : ((n_g - 1) / 24);
                int dq = g - base; dq = dq < -14 ? -14 : (dq > 14 ? 14 : dq);
                t = dq + 15;
              }
              atomicAdd(&sm.u.epi.sv_f[n_loc][t], rsacc[sub][gt][r]);
            }
          }
        }
    }
    __syncthreads();
    if (tb == 0) {
      if (tid < 64) {   // denominators from table-0 scatter
        float l = 0.f;
        for (int t = 0; t < 30; ++t) l += sm.u.epi.sv_f[tid][t];
        sm.l_s[tid] = l;
      }
      // scale P.V part only (before any sv.tv accumulation)
      for (int sub = 0; sub < 2; ++sub)
        for (int ds = 0; ds < 2; ++ds)
          for (int r = 0; r < 4; ++r) oacc[sub][ds][r] *= w;
    }
    // O += sv . tv^T  (A built from sv_f, B from global tvb)
    bf16x8_t av[2];
    for (int sub = 0; sub < 2; ++sub) {
      int n_loc = rg * 32 + sub * 16 + l15;
      for (int j = 0; j < 8; ++j) {
        int t = quad * 8 + j;
        float f = (t < 30) ? sm.u.epi.sv_f[n_loc][t] : 0.f;
        unsigned u = __builtin_bit_cast(unsigned, f);
        av[sub][j] = (short)((u + 0x8000u) >> 16);
      }
    }
    for (int ds = 0; ds < 2; ++ds) {
      bf16x8_t bb = *(const bf16x8_t*)(tvb + ((size_t)(tb * 64 + cg * 32 + ds * 16 + l15)) * 32 + quad * 8);
      for (int sub = 0; sub < 2; ++sub)
        oacc[sub][ds] = __builtin_amdgcn_mfma_f32_16x16x32_bf16(av[sub], bb, oacc[sub][ds], 0, 0, 0);
    }
    __syncthreads();   // sv_f reads done before next tb's zeroing
  }
  // normalize + store (l_s barrier-ordered above)
  float* ob = out + (size_t)b * NTOK * 768 + h * 64;
  for (int sub = 0; sub < 2; ++sub)
    for (int r = 0; r < 4; ++r) {
      int n_loc = rg * 32 + sub * 16 + quad * 4 + r;
      int n_g = n0 + n_loc;
      if (n_g < NTOK) {
        float inv = 1.f / sm.l_s[n_loc];
        for (int ds = 0; ds < 2; ++ds) {
          int d = cg * 32 + ds * 16 + l15;
          ob[(size_t)n_g * 768 + d] = oacc[sub][ds][r] * inv;
        }
      }
    }
}

extern "C" void kernel_launch(void* const* d_in, const int* in_sizes, int n_in,
                              void* d_out, int out_size, void* d_ws, size_t ws_size,
                              hipStream_t stream) {
  const float* x   = (const float*)d_in[0];
  const float* wts = (const float*)d_in[1];
  const float* tkv = (const float*)d_in[2];
  const float* tkh = (const float*)d_in[3];
  const float* tvv = (const float*)d_in[4];
  const float* tvh = (const float*)d_in[5];
  float* out = (float*)d_out;
  const int B = in_sizes[0] / (NTOK * 2304);

  unsigned short* ws = (unsigned short*)d_ws;
  size_t qkSz = (size_t)B * 12 * QPAD * 64;   // == B * VTILES * VTILE_ELEMS
  unsigned short* qbf = ws;
  unsigned short* kbf = ws + qkSz;
  unsigned short* vbf = ws + 2 * qkSz;
  unsigned short* tkb = vbf + qkSz;
  unsigned short* tvb = tkb + (size_t)12 * 2 * 32 * 64;
  unsigned short* gfb = tvb + (size_t)2 * 64 * 32;   // 2*19*2*64*8 shorts = 77824 B

  prep_x3<<<dim3(VTILES, B), 256, 0, stream>>>(x, wts, qbf, kbf, vbf);
  prep_tab<<<dim3(68, 1, 1), 256, 0, stream>>>(wts, tkv, tkh, tvv, tvh, tkb, tvb, gfb);
  hma_kernel<<<dim3(10, 12, B), 256, 0, stream>>>(qbf, kbf, vbf, tkb, tvb, gfb, wts, out);
}

// Round 9
// 250.790 us; speedup vs baseline: 1.3608x; 1.3608x over previous
//
#include <hip/hip_runtime.h>

typedef short bf16x8_t __attribute__((ext_vector_type(8)));
typedef float f32x4_t __attribute__((ext_vector_type(4)));

#define NTOK 577
#define QPAD 640   // q/k row padding (rows 577..639 zeroed)
#define MPAD 608   // m range actually iterated (19*32)
#define NSTEP 19
#define VTILES 80  // v tiles of 8 tokens each (covers n 0..639, pad zeroed)
#define VTILE_ELEMS 6144  // 768 hd * 8 n
#define LOG2E 1.44269504088896340736f

__device__ __forceinline__ unsigned short f2bf(float f) {  // RNE (prepass only)
  unsigned u = __builtin_bit_cast(unsigned, f);
  u += 0x7FFFu + ((u >> 16) & 1u);
  return (unsigned short)(u >> 16);
}
__device__ __forceinline__ float headw(const float* wts, int h) {
  float w0 = wts[0], w1 = wts[1], w2 = wts[2];
  return (h < 8) ? (w0 + w1 + w2) : ((h < 10) ? (w1 + w2) : w2);
}
__device__ __forceinline__ unsigned rangemask(int lo, int hi) {
  lo = lo < 0 ? 0 : lo; hi = hi > 32 ? 32 : hi;
  if (hi <= lo) return 0u;
  unsigned mh = (hi >= 32) ? 0xFFFFFFFFu : ((1u << hi) - 1u);
  unsigned ml = (1u << lo) - 1u;
  return mh & ~ml;
}

// ---------------- prepass v3: 8-token tiles, all sides coalesced ----------------
// q prescale includes LOG2E: logits emerge in log2 domain -> exp2 in hma.
extern "C" __global__ __launch_bounds__(256) void prep_x3(
    const float* __restrict__ x, const float* __restrict__ wts,
    unsigned short* __restrict__ qbf, unsigned short* __restrict__ kbf,
    unsigned short* __restrict__ vbf) {
  __shared__ unsigned short vT[8][768];    // 12288 B
  const int tid = threadIdx.x;
  const int mc = blockIdx.x;               // 0..79
  const int n0 = mc * 8;
  const int b = blockIdx.y;
  const float w0 = wts[0], w1 = wts[1], w2 = wts[2];
  const float wA = w0 + w1 + w2, wB = w1 + w2, wC = w2;
  const float* xb = x + (size_t)b * NTOK * 2304;
#pragma unroll 2
  for (int p = 0; p < 18; ++p) {           // 8 rows x 576 float4 = 4608 / 256
    int i = p * 256 + tid;
    int nl = i / 576;
    int c4 = i - nl * 576;
    int n = n0 + nl;
    float4 v = {0.f, 0.f, 0.f, 0.f};
    if (n < NTOK) v = *(const float4*)(xb + (size_t)n * 2304 + c4 * 4);
    int sec = c4 / 192;                    // 0=q 1=k 2=v (wave-uniform: 576=9*64)
    int cc = c4 - sec * 192;
    int h = cc >> 4, d4 = cc & 15;
    if (sec == 2) {
      ushort4 o;
      o.x = f2bf(v.x); o.y = f2bf(v.y); o.z = f2bf(v.z); o.w = f2bf(v.w);
      *(ushort4*)&vT[nl][cc * 4] = o;
    } else {
      float s = 1.f;
      if (sec == 0) {
        float w = (h < 8) ? wA : ((h < 10) ? wB : wC);
        s = w * w * 0.125f * LOG2E;
      }
      ushort4 o;
      o.x = f2bf(v.x * s); o.y = f2bf(v.y * s); o.z = f2bf(v.z * s); o.w = f2bf(v.w * s);
      unsigned short* dst = (sec == 0) ? qbf : kbf;
      *(ushort4*)(dst + ((size_t)(b * 12 + h)) * QPAD * 64 + (size_t)n * 64 + d4 * 4) = o;
    }
  }
  __syncthreads();
  unsigned short* tile = vbf + (size_t)(b * VTILES + mc) * VTILE_ELEMS;
#pragma unroll
  for (int t = 0; t < 3; ++t) {
    int hd = t * 256 + tid;
    bf16x8_t val;
#pragma unroll
    for (int jj = 0; jj < 8; ++jj) val[jj] = (short)vT[jj][hd];
    *(bf16x8_t*)(tile + (size_t)hd * 8) = val;
  }
}

// ---------------- prepass: tables + precomputed G-fragments ----------------
extern "C" __global__ __launch_bounds__(256) void prep_tab(
    const float* __restrict__ wts,
    const float* __restrict__ tkv, const float* __restrict__ tkh,
    const float* __restrict__ tvv, const float* __restrict__ tvh,
    unsigned short* __restrict__ tkb, unsigned short* __restrict__ tvb,
    unsigned short* __restrict__ gfb) {
  int tid = threadIdx.x, bx = blockIdx.x;
  if (bx < 48) {
    int cid = bx * 256 + tid;
    int d4 = cid & 15, t = (cid >> 4) & 31, tb = (cid >> 9) & 1, h = cid >> 10;
    float s = 1.f / headw(wts, h);
    const float* src = tb ? tkh : tkv;
    float4 v = {0,0,0,0};
    if (t < 30) v = *(const float4*)(src + t * 64 + d4 * 4);
    ushort4 o;
    o.x = f2bf(v.x * s); o.y = f2bf(v.y * s); o.z = f2bf(v.z * s); o.w = f2bf(v.w * s);
    *(ushort4*)(tkb + (((size_t)(h * 2 + tb)) * 32 + t) * 64 + d4 * 4) = o;
  } else if (bx == 48) {
    for (int i = 0; i < 16; ++i) {
      int id = tid * 16 + i;              // 4096 = 2*64*32, t fastest
      int t = id & 31, d = (id >> 5) & 63, tb = id >> 11;
      const float* src = tb ? tvh : tvv;
      tvb[id] = (t < 30) ? f2bf(src[t * 64 + d]) : (unsigned short)0;
    }
  } else {
    int id = (bx - 49) * 256 + tid;       // 0..4863 = ((tb*19+step)*2+gt)*64+lane
    int lane = id & 63, gt = (id >> 6) & 1;
    int sg = id >> 7;                     // tb*19+step
    int step = sg % 19, tb = sg / 19;
    int l15 = lane & 15, quad = lane >> 4;
    int g = gt * 16 + l15;
    int m0 = step * 32;
    unsigned mask = 0u;
    if (g < 25) {
      if (g == 24) {
        mask = rangemask(NTOK - m0, MPAD - m0);
        if (step == 0) mask |= 1u;
      } else if (tb == 0) {
        mask = rangemask(24 * g + 1 - m0, 24 * g + 25 - m0);
      } else {
        int j0 = (g + 1 - m0) % 24; if (j0 < 0) j0 += 24;
        for (int j = j0; j < 32; j += 24) {
          int m = m0 + j;
          if (m >= 1 && m < NTOK) mask |= (1u << j);
        }
      }
    }
    unsigned short o[8];
#pragma unroll
    for (int j = 0; j < 8; ++j) {
      int m_loc = quad * 8 + j;
      o[j] = ((mask >> m_loc) & 1u) ? (unsigned short)0x3F80 : (unsigned short)0;
    }
    *(ushort4*)(gfb + (size_t)id * 8) = *(ushort4*)&o[0];
    *(ushort4*)(gfb + (size_t)id * 8 + 4) = *(ushort4*)&o[4];
  }
}

// ---------------- main kernel v9: R8 structure, launch_bounds(256,4) ----------------
// Same passing kernel as R8; only the register cap is relaxed back to the
// known-good (256,4) -> VGPR ~60, no spills. LDS 25.1KB allows 6 blocks/CU.
struct __align__(16) SMem {
  float qg_t[2][25][68];               // 13600 B  bias by group, g-major (pad 68 for b128)
  float l_s[64];                       // 256 B    softmax denominators
  union {                              // 11264 B
    struct { float qv_t[64][30]; } pro;              // 7680 (one tb at a time)
    struct { unsigned short P_s[2][64][44]; } loop;  // 11264 (double-buffered)
    struct { float sv_f[64][30]; } epi;              // 7680 (one tb at a time)
  } u;
};  // 25120 B -> 6 blocks/CU (LDS-limited; VGPR 60 allows 8 waves/EU)

extern "C" __global__ __launch_bounds__(256, 4) void hma_kernel(
    const unsigned short* __restrict__ qbf, const unsigned short* __restrict__ kbf,
    const unsigned short* __restrict__ vbf, const unsigned short* __restrict__ tkb,
    const unsigned short* __restrict__ tvb, const unsigned short* __restrict__ gfb,
    const float* __restrict__ wts, float* __restrict__ out) {
  __shared__ SMem sm;
  const int tid = threadIdx.x;
  const int wave = tid >> 6, lane = tid & 63, quad = lane >> 4, l15 = lane & 15;
  const int rg = wave & 1;      // n-half (32 rows)
  const int cg = wave >> 1;     // m-half within step / d-half / table id
  const int tb_w = cg;
  // XCD swizzle: colocate the 10 n-tiles of each (b,h) on one XCD (120*B % 8 == 0 always)
  const int nwg = gridDim.x * gridDim.y * gridDim.z;
  const int L = blockIdx.x + gridDim.x * (blockIdx.y + gridDim.y * blockIdx.z);
  const int wid = (L & 7) * (nwg >> 3) + (L >> 3);
  const int n0 = (wid % 10) * 64;
  const int rest = wid / 10;
  const int h = rest % 12, b = rest / 12;
  const float w = headw(wts, h);

  const unsigned short* qb = qbf + ((size_t)(b * 12 + h)) * QPAD * 64;
  const unsigned short* kb = kbf + ((size_t)(b * 12 + h)) * QPAD * 64;
  const unsigned short* gfp = gfb + ((size_t)tb_w * 19) * 1024 + lane * 8;

  // q fragments: registers only, straight from global (pre-scaled bf16)
  bf16x8_t qa[2][2];
  for (int sub = 0; sub < 2; ++sub)
    for (int kk = 0; kk < 2; ++kk)
      qa[sub][kk] = *(const bf16x8_t*)(qb + (size_t)(n0 + rg * 32 + sub * 16 + l15) * 64 + kk * 32 + quad * 8);

  // ---- prologue: bias tables, one tb at a time (half the scratch) ----
  for (int tb = 0; tb < 2; ++tb) {
    const unsigned short* tkp = tkb + ((size_t)(h * 2 + tb)) * 32 * 64;
    const int tt = cg;
    for (int sub = 0; sub < 2; ++sub) {
      f32x4_t acc = {0.f, 0.f, 0.f, 0.f};
      for (int kk = 0; kk < 2; ++kk) {
        bf16x8_t bb = *(const bf16x8_t*)(tkp + (size_t)(tt * 16 + l15) * 64 + kk * 32 + quad * 8);
        acc = __builtin_amdgcn_mfma_f32_16x16x32_bf16(qa[sub][kk], bb, acc, 0, 0, 0);
      }
      int t = tt * 16 + l15;
      if (t < 30)
        for (int r = 0; r < 4; ++r)
          sm.u.pro.qv_t[rg * 32 + sub * 16 + quad * 4 + r][t] = acc[r];
    }
    __syncthreads();
    // pre-scatter rel-k bias by group (transposed: qg_t[tb][g][n])
    for (int p = tid; p < 25 * 64; p += 256) {
      int g = p / 64, n = p % 64;
      int n_g = n0 + n;
      int t;
      if (n_g == 0 || n_g >= NTOK || g == 24) t = 0;
      else {
        int base = tb ? ((n_g - 1) % 24) : ((n_g - 1) / 24);
        int dq = g - base; dq = dq < -14 ? -14 : (dq > 14 ? 14 : dq);
        t = dq + 15;
      }
      sm.qg_t[tb][g][n] = sm.u.pro.qv_t[n][t];
    }
    __syncthreads();   // qv_t reads done before next tb overwrite / loop union reuse
  }

  // per-thread m-group trackers
  const int m_loc = cg * 16 + l15;
  int rmv, cmv;
  if (m_loc == 0) { rmv = 0; cmv = -1; }
  else { rmv = (m_loc - 1) / 24; cmv = (m_loc - 1) - rmv * 24; }
  const bool cls_lane = (m_loc == 0);

  f32x4_t oacc[2][2] = {{{0,0,0,0},{0,0,0,0}},{{0,0,0,0},{0,0,0,0}}};
  f32x4_t rsacc[2][2] = {{{0,0,0,0},{0,0,0,0}},{{0,0,0,0},{0,0,0,0}}};

  // direct-global fragment base pointers
  const unsigned short* kfr = kb + (size_t)(cg * 16 + l15) * 64 + quad * 8;
  const unsigned short* vfr = vbf + (size_t)b * VTILES * VTILE_ELEMS + h * 512
                              + (size_t)(cg * 32 + l15) * 8;
  bf16x8_t kf0 = *(const bf16x8_t*)(kfr);        // step 0 k-frags (rows 0..31)
  bf16x8_t kf1 = *(const bf16x8_t*)(kfr + 32);

  for (int step = 0; step < NSTEP; ++step) {
    const int m0 = step * 32;
    const int buf = step & 1;
    // G fragments for this step (L2-hot; issue early, use late)
    bf16x8_t gv0 = *(const bf16x8_t*)(gfp + (size_t)step * 1024);
    bf16x8_t gv1 = *(const bf16x8_t*)(gfp + (size_t)step * 1024 + 512);
    // S = q_hat . k^T  (two n-subtiles per wave) — k frags already in regs
    f32x4_t s[2] = {{0,0,0,0},{0,0,0,0}};
    for (int sub = 0; sub < 2; ++sub) {
      s[sub] = __builtin_amdgcn_mfma_f32_16x16x32_bf16(qa[sub][0], kf0, s[sub], 0, 0, 0);
      s[sub] = __builtin_amdgcn_mfma_f32_16x16x32_bf16(qa[sub][1], kf1, s[sub], 0, 0, 0);
    }
    // v B-frags for THIS step: contiguous 16B/lane from tiled vbf (issue early)
    const unsigned short* vt = vfr + (size_t)(m0 / 8 + quad) * VTILE_ELEMS;
    bf16x8_t vf0 = *(const bf16x8_t*)(vt);
    bf16x8_t vf1 = *(const bf16x8_t*)(vt + 128);
    // k prefetch for NEXT step (rows 608..639 are zero pad on last iter)
    kf0 = *(const bf16x8_t*)(kfr + (size_t)(m0 + 32) * 64);
    kf1 = *(const bf16x8_t*)(kfr + (size_t)(m0 + 32) * 64 + 32);
    // rel bias + exp2 -> P (logits already in log2 domain via q prescale)
    const int m_g = m0 + m_loc;
    int ur = rmv, uc = cmv;
    if (cls_lane && step == 0) { ur = 24; uc = 24; }
    const bool mpad = (m_g >= NTOK);
    for (int sub = 0; sub < 2; ++sub) {
      int nbase = rg * 32 + sub * 16 + quad * 4;
      f32x4_t g0 = *(const f32x4_t*)&sm.qg_t[0][ur][nbase];
      f32x4_t g1 = *(const f32x4_t*)&sm.qg_t[1][uc][nbase];
      for (int r = 0; r < 4; ++r) {
        float logit = s[sub][r] + g0[r] + g1[r];
        float p = __builtin_exp2f(logit);
        if (mpad) p = 0.f;
        unsigned u = __builtin_bit_cast(unsigned, p);
        sm.u.loop.P_s[buf][nbase + r][m_loc] = (unsigned short)((u + 0x8000u) >> 16);
      }
    }
    { int c = cmv + 8; int carry = (c >= 24); cmv = carry ? c - 24 : c; rmv += 1 + carry; }
    __syncthreads();                           // P_s[buf] ready (only barrier per step)
    // A fragments (P) shared by PV and G
    bf16x8_t pa[2];
    for (int sub = 0; sub < 2; ++sub)
      pa[sub] = *(const bf16x8_t*)&sm.u.loop.P_s[buf][rg * 32 + sub * 16 + l15][quad * 8];
    // O += P.V  (v frags from regs)
    for (int sub = 0; sub < 2; ++sub) {
      oacc[sub][0] = __builtin_amdgcn_mfma_f32_16x16x32_bf16(pa[sub], vf0, oacc[sub][0], 0, 0, 0);
      oacc[sub][1] = __builtin_amdgcn_mfma_f32_16x16x32_bf16(pa[sub], vf1, oacc[sub][1], 0, 0, 0);
    }
    // rowsum += P.G
    for (int sub = 0; sub < 2; ++sub) {
      rsacc[sub][0] = __builtin_amdgcn_mfma_f32_16x16x32_bf16(pa[sub], gv0, rsacc[sub][0], 0, 0, 0);
      rsacc[sub][1] = __builtin_amdgcn_mfma_f32_16x16x32_bf16(pa[sub], gv1, rsacc[sub][1], 0, 0, 0);
    }
  }

  // ---- epilogue: one tb at a time through the halved sv scratch ----
  __syncthreads();   // last P_s reads done before union reuse
  for (int tb = 0; tb < 2; ++tb) {
    for (int e = tid; e < 64 * 30; e += 256) (&sm.u.epi.sv_f[0][0])[e] = 0.f;
    __syncthreads();
    if (cg == tb) {    // this wave's rsacc belongs to table tb
      for (int sub = 0; sub < 2; ++sub)
        for (int gt = 0; gt < 2; ++gt) {
          int g = gt * 16 + l15;
          if (g < 25) {
            for (int r = 0; r < 4; ++r) {
              int n_loc = rg * 32 + sub * 16 + quad * 4 + r;
              int n_g = n0 + n_loc;
              int t;
              if (n_g == 0 || n_g >= NTOK || g == 24) t = 0;
              else {
                int base = tb ? ((n_g - 1) % 24) : ((n_g - 1) / 24);
                int dq = g - base; dq = dq < -14 ? -14 : (dq > 14 ? 14 : dq);
                t = dq + 15;
              }
              atomicAdd(&sm.u.epi.sv_f[n_loc][t], rsacc[sub][gt][r]);
            }
          }
        }
    }
    __syncthreads();
    if (tb == 0) {
      if (tid < 64) {   // denominators from table-0 scatter
        float l = 0.f;
        for (int t = 0; t < 30; ++t) l += sm.u.epi.sv_f[tid][t];
        sm.l_s[tid] = l;
      }
      // scale P.V part only (before any sv.tv accumulation)
      for (int sub = 0; sub < 2; ++sub)
        for (int ds = 0; ds < 2; ++ds)
          for (int r = 0; r < 4; ++r) oacc[sub][ds][r] *= w;
    }
    // O += sv . tv^T  (A built from sv_f, B from global tvb)
    bf16x8_t av[2];
    for (int sub = 0; sub < 2; ++sub) {
      int n_loc = rg * 32 + sub * 16 + l15;
      for (int j = 0; j < 8; ++j) {
        int t = quad * 8 + j;
        float f = (t < 30) ? sm.u.epi.sv_f[n_loc][t] : 0.f;
        unsigned u = __builtin_bit_cast(unsigned, f);
        av[sub][j] = (short)((u + 0x8000u) >> 16);
      }
    }
    for (int ds = 0; ds < 2; ++ds) {
      bf16x8_t bb = *(const bf16x8_t*)(tvb + ((size_t)(tb * 64 + cg * 32 + ds * 16 + l15)) * 32 + quad * 8);
      for (int sub = 0; sub < 2; ++sub)
        oacc[sub][ds] = __builtin_amdgcn_mfma_f32_16x16x32_bf16(av[sub], bb, oacc[sub][ds], 0, 0, 0);
    }
    __syncthreads();   // sv_f reads done before next tb's zeroing
  }
  // normalize + store (l_s barrier-ordered above)
  float* ob = out + (size_t)b * NTOK * 768 + h * 64;
  for (int sub = 0; sub < 2; ++sub)
    for (int r = 0; r < 4; ++r) {
      int n_loc = rg * 32 + sub * 16 + quad * 4 + r;
      int n_g = n0 + n_loc;
      if (n_g < NTOK) {
        float inv = 1.f / sm.l_s[n_loc];
        for (int ds = 0; ds < 2; ++ds) {
          int d = cg * 32 + ds * 16 + l15;
          ob[(size_t)n_g * 768 + d] = oacc[sub][ds][r] * inv;
        }
      }
    }
}

extern "C" void kernel_launch(void* const* d_in, const int* in_sizes, int n_in,
                              void* d_out, int out_size, void* d_ws, size_t ws_size,
                              hipStream_t stream) {
  const float* x   = (const float*)d_in[0];
  const float* wts = (const float*)d_in[1];
  const float* tkv = (const float*)d_in[2];
  const float* tkh = (const float*)d_in[3];
  const float* tvv = (const float*)d_in[4];
  const float* tvh = (const float*)d_in[5];
  float* out = (float*)d_out;
  const int B = in_sizes[0] / (NTOK * 2304);

  unsigned short* ws = (unsigned short*)d_ws;
  size_t qkSz = (size_t)B * 12 * QPAD * 64;   // == B * VTILES * VTILE_ELEMS
  unsigned short* qbf = ws;
  unsigned short* kbf = ws + qkSz;
  unsigned short* vbf = ws + 2 * qkSz;
  unsigned short* tkb = vbf + qkSz;
  unsigned short* tvb = tkb + (size_t)12 * 2 * 32 * 64;
  unsigned short* gfb = tvb + (size_t)2 * 64 * 32;   // 2*19*2*64*8 shorts = 77824 B

  prep_x3<<<dim3(VTILES, B), 256, 0, stream>>>(x, wts, qbf, kbf, vbf);
  prep_tab<<<dim3(68, 1, 1), 256, 0, stream>>>(wts, tkv, tkh, tvv, tvh, tkb, tvb, gfb);
  hma_kernel<<<dim3(10, 12, B), 256, 0, stream>>>(qbf, kbf, vbf, tkb, tvb, gfb, wts, out);
}